// Round 12
// baseline (192.135 us; speedup 1.0000x reference)
//
#include <hip/hip_runtime.h>
#include <hip/hip_bf16.h>
#include <cmath>

// VNAttention MI355X: B=4, C=256, N=2048, H=8, HD=32, F=96, BH=32
// f-enumeration: f = i*32 + cw
// Pipeline:
//   1) wconv    : Wq*SCALE_LOG2, Wk, Wv, Wo -> bf16 [1024][256]
//   2) xt       : x -> xt bf16 [(b,i)][n][c]
//   3) qkv_gemm : Qt,Kt token-major [bh][n][96]; Vf feature-major [bh][96][n]
//   4) attn     : swapped-QK^T 32x32 MFMA, max-free softmax, split-K=2,
//                 BARRIER-FREE: K/V fragments read directly from global
//                 (L1/L2-resident; 16 blocks + 4 waves share every byte).
//                 No LDS staging in the main loop; waves drift freely.
//   5) out_gemm : split-K combine (lerp by l0/(l0+l1)) fused into staging.

typedef unsigned short u16;
typedef unsigned int   u32;
typedef u16   u16x8  __attribute__((ext_vector_type(8)));
typedef short s16x8  __attribute__((ext_vector_type(8)));
typedef float f32x4  __attribute__((ext_vector_type(4)));
typedef float f32x16 __attribute__((ext_vector_type(16)));

namespace {
constexpr int Nc = 2048, Fc = 96;
constexpr float SCALE_LOG2 = 0.17677669529663687f * 1.4426950408889634f;
}

__device__ inline float fast_exp2(float x) {
#if __has_builtin(__builtin_amdgcn_exp2f)
    return __builtin_amdgcn_exp2f(x);
#else
    return exp2f(x);
#endif
}

__device__ inline u16 f2bf(float x) {   // RNE f32 -> bf16 bits
    union { float f; unsigned u; } v; v.f = x;
    unsigned r = v.u + 0x7FFFu + ((v.u >> 16) & 1u);
    return (u16)(r >> 16);
}

__device__ inline float bf2f(u16 x) {
    union { unsigned u; float f; } v; v.u = ((unsigned)x) << 16; return v.f;
}

// ---------------------------------------------------------------------------
// 1) weight conversion
// ---------------------------------------------------------------------------
__global__ __launch_bounds__(256) void wconv_kernel(
    const float* __restrict__ Wq, const float* __restrict__ Wk,
    const float* __restrict__ Wv, const float* __restrict__ Wo,
    u16* __restrict__ Wb)
{
    const int id = blockIdx.x * 256 + threadIdx.x;
    const int base = id * 8;
    const int o = base >> 8, c = base & 255;
    const int sel = o >> 8, ol = o & 255;
    const float* src = (sel == 0) ? Wq : (sel == 1) ? Wk : (sel == 2) ? Wv : Wo;
    const float sc = (sel == 0) ? SCALE_LOG2 : 1.0f;
    const float4 a = *(const float4*)&src[(size_t)ol * 256 + c];
    const float4 b = *(const float4*)&src[(size_t)ol * 256 + c + 4];
    u16x8 r;
    r[0]=f2bf(a.x*sc); r[1]=f2bf(a.y*sc); r[2]=f2bf(a.z*sc); r[3]=f2bf(a.w*sc);
    r[4]=f2bf(b.x*sc); r[5]=f2bf(b.y*sc); r[6]=f2bf(b.z*sc); r[7]=f2bf(b.w*sc);
    *(u16x8*)&Wb[(size_t)o * 256 + c] = r;
}

// ---------------------------------------------------------------------------
// 2) x f32 [b][c][i][n] -> xt bf16 [(b*3+i)][n][c]
// ---------------------------------------------------------------------------
__global__ __launch_bounds__(256) void xt_kernel(
    const float* __restrict__ x, u16* __restrict__ xt)
{
    const int nt = blockIdx.x, ct = blockIdx.y, bi = blockIdx.z;
    const int b = bi / 3, i = bi % 3;
    const int t = (int)threadIdx.x;
    const int n0 = nt * 64, c0 = ct * 64;

    __shared__ u16 tile[64][72];

    const int n_l = t & 63;
#pragma unroll
    for (int it = 0; it < 16; ++it) {
        const int c_l = (t >> 6) + it * 4;
        tile[n_l][c_l] =
            f2bf(x[(((size_t)(b * 256 + c0 + c_l)) * 3 + i) * Nc + n0 + n_l]);
    }
    __syncthreads();
#pragma unroll
    for (int it = 0; it < 2; ++it) {
        const int idx = t + it * 256;
        const int nn = idx >> 3, part = idx & 7;
        *(u16x8*)&xt[((size_t)bi * Nc + n0 + nn) * 256 + c0 + part * 8] =
            *(const u16x8*)&tile[nn][part * 8];
    }
}

// ---------------------------------------------------------------------------
// 3) QKV GEMM (128x128 tile, 4 waves)
// ---------------------------------------------------------------------------
__global__ __launch_bounds__(256) void qkv_gemm_kernel(
    const u16* __restrict__ xt, const u16* __restrict__ wb,
    u16* __restrict__ Qt, u16* __restrict__ Kt, u16* __restrict__ Vf)
{
    const int nt = blockIdx.x;
    const int wy = blockIdx.y;
    const int bi = blockIdx.z;
    const int b = bi / 3, i = bi % 3;
    const int wsel = wy >> 1, ot = wy & 1;

    const u16* xs = xt + ((size_t)bi * Nc + nt * 128) * 256;
    const u16* ws = wb + (size_t)(wsel * 256 + ot * 128) * 256;

    __shared__ u16 xl[128][40];
    __shared__ u16 wl[128][40];

    const int t = (int)threadIdx.x;
    const int wv = t >> 6, lane = t & 63;
    const int g = lane >> 4, c16 = lane & 15;
    const int wr = wv >> 1, wc = wv & 1;

    f32x4 acc[4][4];
#pragma unroll
    for (int mi = 0; mi < 4; ++mi)
#pragma unroll
        for (int ni = 0; ni < 4; ++ni)
#pragma unroll
            for (int r = 0; r < 4; ++r) acc[mi][ni][r] = 0.f;

    for (int ks = 0; ks < 8; ++ks) {
        __syncthreads();
#pragma unroll
        for (int it = 0; it < 2; ++it) {
            const int idx = t + it * 256;
            const int row = idx >> 2, part = idx & 3;
            *(u16x8*)&xl[row][part * 8] =
                *(const u16x8*)&xs[(size_t)row * 256 + ks * 32 + part * 8];
            *(u16x8*)&wl[row][part * 8] =
                *(const u16x8*)&ws[(size_t)row * 256 + ks * 32 + part * 8];
        }
        __syncthreads();

        s16x8 af[4], bf[4];
        if (wsel < 2) {
#pragma unroll
            for (int mi = 0; mi < 4; ++mi) af[mi] = *(const s16x8*)&xl[wr*64 + mi*16 + c16][g*8];
#pragma unroll
            for (int ni = 0; ni < 4; ++ni) bf[ni] = *(const s16x8*)&wl[wc*64 + ni*16 + c16][g*8];
        } else {
#pragma unroll
            for (int mi = 0; mi < 4; ++mi) af[mi] = *(const s16x8*)&wl[wr*64 + mi*16 + c16][g*8];
#pragma unroll
            for (int ni = 0; ni < 4; ++ni) bf[ni] = *(const s16x8*)&xl[wc*64 + ni*16 + c16][g*8];
        }
#pragma unroll
        for (int mi = 0; mi < 4; ++mi)
#pragma unroll
            for (int ni = 0; ni < 4; ++ni)
                acc[mi][ni] = __builtin_amdgcn_mfma_f32_16x16x32_bf16(
                    af[mi], bf[ni], acc[mi][ni], 0, 0, 0);
    }

    if (wsel < 2) {
        u16* dst = wsel ? Kt : Qt;
#pragma unroll
        for (int mi = 0; mi < 4; ++mi)
#pragma unroll
            for (int ni = 0; ni < 4; ++ni) {
                const int o = ot * 128 + wc * 64 + ni * 16 + c16;
                const int h = o >> 5, cw = o & 31;
#pragma unroll
                for (int r = 0; r < 4; ++r) {
                    const int n = nt * 128 + wr * 64 + mi * 16 + g * 4 + r;
                    dst[((size_t)(b * 8 + h) * Nc + n) * Fc + i * 32 + cw] =
                        f2bf(acc[mi][ni][r]);
                }
            }
    } else {
#pragma unroll
        for (int mi = 0; mi < 4; ++mi)
#pragma unroll
            for (int ni = 0; ni < 4; ++ni) {
                const int n = nt * 128 + wc * 64 + ni * 16 + c16;
#pragma unroll
                for (int r = 0; r < 4; ++r) {
                    const int o = ot * 128 + wr * 64 + mi * 16 + g * 4 + r;
                    const int h = o >> 5, cw = o & 31;
                    Vf[((size_t)(b * 8 + h) * Fc + i * 32 + cw) * Nc + n] =
                        f2bf(acc[mi][ni][r]);
                }
            }
    }
}

// ---------------------------------------------------------------------------
// 4) attention: barrier-free. K/V MFMA A-fragments read directly from
//    global (L1/L2). Block = (bh, qt, half): 128 q x 1024 keys; per wave
//    32 q x 32-key tiles. Max-free softmax. LDS used only for the per-wave
//    epilogue transpose (wave-local -> lgkmcnt sync, no block barrier).
// ---------------------------------------------------------------------------
__global__ __launch_bounds__(256) void attn_mfma_kernel(
    const u16* __restrict__ Qt, const u16* __restrict__ Kt,
    const u16* __restrict__ Vf, u16* __restrict__ obt, float* __restrict__ lP)
{
    // XCD-aware swizzle: 1024 blocks, 128 per XCD -> XCD k owns bh [4k,4k+4)
    const int bid = (int)blockIdx.x;
    const int lid = (bid & 7) * 128 + (bid >> 3);
    const int bh   = lid >> 5;
    const int r5   = lid & 31;
    const int qt   = r5 >> 1;        // 0..15
    const int half = r5 & 1;         // key half

    const int t_   = (int)threadIdx.x;
    const int wq   = t_ >> 6;
    const int lane = t_ & 63;
    const int ql   = lane & 31;      // query col / K,V A-frag row
    const int hi   = lane >> 5;

    __shared__ u16 tbuf[4][3328];    // per-wave epilogue transpose (26.6 KB)

    const int qb = qt * 128 + wq * 32;
    const int k0 = half * 1024;

    // Q B-frags: lane holds Q[qb+ql][16*s6 + 8*hi + j], j=0..7
    s16x8 bq[6];
#pragma unroll
    for (int s6 = 0; s6 < 6; ++s6)
        bq[s6] = *(const s16x8*)&Qt[((size_t)bh * Nc + qb + ql) * Fc + s6 * 16 + hi * 8];

    // direct global fragment pointers (advance per 32-key tile)
    const u16* kp  = Kt + ((size_t)bh * Nc + k0 + ql) * Fc + hi * 8;     // K row ql
    const u16* vp0 = Vf + ((size_t)bh * Fc +  0 + ql) * Nc + k0 + hi * 8;
    const u16* vp1 = Vf + ((size_t)bh * Fc + 32 + ql) * Nc + k0 + hi * 8;
    const u16* vp2 = Vf + ((size_t)bh * Fc + 64 + ql) * Nc + k0 + hi * 8;

    f32x16 acc[3];
#pragma unroll
    for (int ft = 0; ft < 3; ++ft)
#pragma unroll
        for (int r = 0; r < 16; ++r) acc[ft][r] = 0.f;
    float lacc[8];
#pragma unroll
    for (int r = 0; r < 8; ++r) lacc[r] = 0.f;

    for (int kt = 0; kt < 32; ++kt) {
        // issue all 12 fragment loads (ka first -> counted vmcnt lets va
        // stay in flight through QK + softmax)
        s16x8 ka[6], va[6];
#pragma unroll
        for (int s6 = 0; s6 < 6; ++s6)
            ka[s6] = *(const s16x8*)(kp + s6 * 16);
        va[0] = *(const s16x8*)(vp0);      va[1] = *(const s16x8*)(vp0 + 16);
        va[2] = *(const s16x8*)(vp1);      va[3] = *(const s16x8*)(vp1 + 16);
        va[4] = *(const s16x8*)(vp2);      va[5] = *(const s16x8*)(vp2 + 16);
        kp += 32 * Fc; vp0 += 32; vp1 += 32; vp2 += 32;

        // QK(kt)
        f32x16 sv;
#pragma unroll
        for (int r = 0; r < 16; ++r) sv[r] = 0.f;
#pragma unroll
        for (int s6 = 0; s6 < 6; ++s6)
            sv = __builtin_amdgcn_mfma_f32_32x32x16_bf16(ka[s6], bq[s6], sv, 0, 0, 0);

        // max-free softmax: P = 2^S
#pragma unroll
        for (int r = 0; r < 16; ++r) sv[r] = fast_exp2(sv[r]);
#pragma unroll
        for (int r = 0; r < 8; ++r) lacc[r] += sv[r] + sv[r + 8];

        // pack P -> bf16 B-frags
        u32 pk8[8];
#pragma unroll
        for (int j = 0; j < 8; ++j)
            asm("v_cvt_pk_bf16_f32 %0, %1, %2" : "=v"(pk8[j]) : "v"(sv[2*j]), "v"(sv[2*j+1]));
        asm volatile("v_permlane32_swap_b32 %0, %1" : "+v"(pk8[0]), "+v"(pk8[2]));
        asm volatile("v_permlane32_swap_b32 %0, %1" : "+v"(pk8[1]), "+v"(pk8[3]));
        asm volatile("v_permlane32_swap_b32 %0, %1" : "+v"(pk8[4]), "+v"(pk8[6]));
        asm volatile("v_permlane32_swap_b32 %0, %1" : "+v"(pk8[5]), "+v"(pk8[7]));
        union U { u32 w[4]; s16x8 v; } pb0, pb1;
        pb0.w[0]=pk8[0]; pb0.w[1]=pk8[1]; pb0.w[2]=pk8[2]; pb0.w[3]=pk8[3];
        pb1.w[0]=pk8[4]; pb1.w[1]=pk8[5]; pb1.w[2]=pk8[6]; pb1.w[3]=pk8[7];

        // PV(kt)
#pragma unroll
        for (int ft = 0; ft < 3; ++ft) {
            acc[ft] = __builtin_amdgcn_mfma_f32_32x32x16_bf16(va[2*ft],     pb0.v, acc[ft], 0, 0, 0);
            acc[ft] = __builtin_amdgcn_mfma_f32_32x32x16_bf16(va[2*ft + 1], pb1.v, acc[ft], 0, 0, 0);
        }
    }

    // ---- epilogue: reduce l, wave-private LDS transpose, token-major stores
    float l4[4];
#pragma unroll
    for (int r = 0; r < 4; ++r) l4[r] = lacc[r] + lacc[r + 4];
    float l_s = (l4[0] + l4[2]) + (l4[1] + l4[3]);
    l_s += __shfl_xor(l_s, 32);
    const float inv = 1.f / l_s;
    if (hi == 0)
        lP[((size_t)half * 32 + bh) * Nc + qb + ql] = l_s;

    u16* ot = &tbuf[wq][0];          // 32 rows x pitch 104, wave-local
#pragma unroll
    for (int ft = 0; ft < 3; ++ft)
#pragma unroll
        for (int r = 0; r < 16; ++r) {
            const int frow = (r & 3) + 8 * (r >> 2) + 4 * hi;
            ot[ql * 104 + ft * 32 + frow] = f2bf(acc[ft][r] * inv);
        }
    asm volatile("s_waitcnt lgkmcnt(0)" ::: "memory");  // wave-local RAW
    __builtin_amdgcn_sched_barrier(0);

    u16x8 v6[6];
#pragma unroll
    for (int j = 0; j < 6; ++j)
        v6[j] = *(const u16x8*)&ot[ql * 104 + hi * 48 + j * 8];

    const int n = qb + ql;
    const int b_ = bh >> 3, h_ = bh & 7;
    const size_t base0 = (((size_t)half * 12 + b_ * 3 + 0) * Nc + n) * 256 + h_ * 32;
    const size_t base1 = (((size_t)half * 12 + b_ * 3 + 1) * Nc + n) * 256 + h_ * 32;
    const size_t base2 = (((size_t)half * 12 + b_ * 3 + 2) * Nc + n) * 256 + h_ * 32;
    if (hi == 0) {   // f 0..47: i=0 cw0..31, i=1 cw0..15
        *(u16x8*)&obt[base0 +  0] = v6[0];
        *(u16x8*)&obt[base0 +  8] = v6[1];
        *(u16x8*)&obt[base0 + 16] = v6[2];
        *(u16x8*)&obt[base0 + 24] = v6[3];
        *(u16x8*)&obt[base1 +  0] = v6[4];
        *(u16x8*)&obt[base1 +  8] = v6[5];
    } else {         // f 48..95: i=1 cw16..31, i=2 cw0..31
        *(u16x8*)&obt[base1 + 16] = v6[0];
        *(u16x8*)&obt[base1 + 24] = v6[1];
        *(u16x8*)&obt[base2 +  0] = v6[2];
        *(u16x8*)&obt[base2 +  8] = v6[3];
        *(u16x8*)&obt[base2 + 16] = v6[4];
        *(u16x8*)&obt[base2 + 24] = v6[5];
    }
}

// ---------------------------------------------------------------------------
// 5) out GEMM + residual, with fused split-K combine in the staging:
//    al[n][c] = w0*obt0 + (1-w0)*obt1, w0 = l0/(l0+l1); head h = ks.
// ---------------------------------------------------------------------------
__global__ __launch_bounds__(256) void out_gemm_kernel(
    const u16* __restrict__ obt, const float* __restrict__ lP,
    const u16* __restrict__ wb, const float* __restrict__ x,
    float* __restrict__ out)
{
    const int nt = blockIdx.x, ot = blockIdx.y, bi = blockIdx.z;
    const int b = bi / 3, i = bi % 3;

    const u16* p0 = obt + ((size_t)bi * Nc) * 256;            // half 0
    const u16* p1 = obt + (((size_t)12 + bi) * Nc) * 256;     // half 1
    const u16* ws = wb + (size_t)(768 + ot * 128) * 256;

    __shared__ u16 al[128][40];
    __shared__ u16 wl[128][40];

    const int t = (int)threadIdx.x;
    const int wv = t >> 6, lane = t & 63;
    const int g = lane >> 4, c16 = lane & 15;
    const int wr = wv >> 1, wc = wv & 1;

    f32x4 acc[4][4];
#pragma unroll
    for (int mi = 0; mi < 4; ++mi)
#pragma unroll
        for (int ni = 0; ni < 4; ++ni)
#pragma unroll
            for (int r = 0; r < 4; ++r) acc[mi][ni][r] = 0.f;

    for (int ks = 0; ks < 8; ++ks) {
        __syncthreads();
#pragma unroll
        for (int it = 0; it < 2; ++it) {
            const int idx = t + it * 256;
            const int row = idx >> 2, part = idx & 3;
            const int n = nt * 128 + row;
            const float l0 = lP[((size_t)(b * 8 + ks)) * Nc + n];
            const float l1 = lP[((size_t)(32 + b * 8 + ks)) * Nc + n];
            const float w0 = l0 / (l0 + l1);
            const float w1 = 1.f - w0;
            const u16x8 a0 = *(const u16x8*)&p0[(size_t)n * 256 + ks * 32 + part * 8];
            const u16x8 a1 = *(const u16x8*)&p1[(size_t)n * 256 + ks * 32 + part * 8];
            u16x8 rr;
#pragma unroll
            for (int j = 0; j < 8; ++j)
                rr[j] = f2bf(bf2f(a0[j]) * w0 + bf2f(a1[j]) * w1);
            *(u16x8*)&al[row][part * 8] = rr;
            *(u16x8*)&wl[row][part * 8] =
                *(const u16x8*)&ws[(size_t)row * 256 + ks * 32 + part * 8];
        }
        __syncthreads();

        s16x8 af[4], bf[4];
#pragma unroll
        for (int mi = 0; mi < 4; ++mi) af[mi] = *(const s16x8*)&wl[wr*64 + mi*16 + c16][g*8];
#pragma unroll
        for (int ni = 0; ni < 4; ++ni) bf[ni] = *(const s16x8*)&al[wc*64 + ni*16 + c16][g*8];
#pragma unroll
        for (int mi = 0; mi < 4; ++mi)
#pragma unroll
            for (int ni = 0; ni < 4; ++ni)
                acc[mi][ni] = __builtin_amdgcn_mfma_f32_16x16x32_bf16(
                    af[mi], bf[ni], acc[mi][ni], 0, 0, 0);
    }

#pragma unroll
    for (int mi = 0; mi < 4; ++mi)
#pragma unroll
        for (int ni = 0; ni < 4; ++ni) {
            const int n = nt * 128 + wc * 64 + ni * 16 + c16;
#pragma unroll
            for (int r = 0; r < 4; ++r) {
                const int o = ot * 128 + wr * 64 + mi * 16 + g * 4 + r;
                const size_t idx = ((size_t)(b * 256 + o) * 3 + i) * Nc + n;
                out[idx] = x[idx] + acc[mi][ni][r];
            }
        }
}

// ---------------------------------------------------------------------------
extern "C" void kernel_launch(void* const* d_in, const int* in_sizes, int n_in,
                              void* d_out, int out_size, void* d_ws, size_t ws_size,
                              hipStream_t stream) {
    const float* x  = (const float*)d_in[0];
    const float* Wq = (const float*)d_in[1];
    const float* Wk = (const float*)d_in[2];
    const float* Wv = (const float*)d_in[3];
    const float* Wo = (const float*)d_in[4];
    float* out = (float*)d_out;

    const size_t E = (size_t)32 * Fc * Nc;       // 6,291,456 u16
    u16* xt  = (u16*)d_ws;                        // E
    u16* wbw = xt + E;                            // 262144
    u16* qt  = wbw + 262144;                      // E
    u16* kt  = qt + E;                            // E
    u16* vf  = kt + E;                            // E
    u16* obt = vf + E;                            // 2*E (token-major partials)
    float* lP = (float*)(obt + 2 * E);            // 131072 floats

    dim3 blk(256);
    wconv_kernel    <<<dim3(128),        blk, 0, stream>>>(Wq, Wk, Wv, Wo, wbw);
    xt_kernel       <<<dim3(32, 4, 12),  blk, 0, stream>>>(x, xt);
    qkv_gemm_kernel <<<dim3(16, 6, 12),  blk, 0, stream>>>(xt, wbw, qt, kt, vf);
    attn_mfma_kernel<<<dim3(1024),       blk, 0, stream>>>(qt, kt, vf, obt, lP);
    out_gemm_kernel <<<dim3(16, 2, 12),  blk, 0, stream>>>(obt, lP, wbw, x, out);
}

// Round 13
// 150.201 us; speedup vs baseline: 1.2792x; 1.2792x over previous
//
#include <hip/hip_runtime.h>
#include <hip/hip_bf16.h>
#include <cmath>

// VNAttention MI355X: B=4, C=256, N=2048, H=8, HD=32, F=96, BH=32
// f-enumeration: f = i*32 + cw
// Pipeline:
//   1) prep     : wconv (Wq*SCALE_LOG2,Wk,Wv,Wo -> bf16) + xt transpose, merged
//   2) qkv_gemm : Qt,Kt token-major [bh][n][96]; Vf feature-major [bh][96][n]
//   3) attn     : r11 structure (swapped-QK^T 32x32 MFMA, KVBLK=32, triple-
//                 buffered QK(t+1)-ahead pipeline, max-free softmax, split-K=2)
//                 + K/V LDS XOR-swizzle (unit ^= (row>>3)&3) killing the
//                 4-way stride-20-dword bank conflicts on ds_read_b128.
//   4) out_gemm : split-K combine (lerp by l0/(l0+l1)) fused into staging.

typedef unsigned short u16;
typedef unsigned int   u32;
typedef u16   u16x8  __attribute__((ext_vector_type(8)));
typedef short s16x8  __attribute__((ext_vector_type(8)));
typedef float f32x4  __attribute__((ext_vector_type(4)));
typedef float f32x16 __attribute__((ext_vector_type(16)));

namespace {
constexpr int Nc = 2048, Fc = 96;
constexpr float SCALE_LOG2 = 0.17677669529663687f * 1.4426950408889634f;
// attn LDS geometry (u16 units): 32-key tiles, triple-buffered
constexpr int KP = 104;              // K row pitch (32 rows x 96 f), 208 B
constexpr int VP = 40;               // V row pitch (96 rows x 32 keys), 80 B
constexpr int VOFF = 32 * KP;        // 3328
constexpr int SBUF = VOFF + 96 * VP; // 7168 u16 = 14336 B per buffer
}

__device__ inline float fast_exp2(float x) {
#if __has_builtin(__builtin_amdgcn_exp2f)
    return __builtin_amdgcn_exp2f(x);
#else
    return exp2f(x);
#endif
}

__device__ inline u16 f2bf(float x) {   // RNE f32 -> bf16 bits
    union { float f; unsigned u; } v; v.f = x;
    unsigned r = v.u + 0x7FFFu + ((v.u >> 16) & 1u);
    return (u16)(r >> 16);
}

__device__ inline float bf2f(u16 x) {
    union { unsigned u; float f; } v; v.u = ((unsigned)x) << 16; return v.f;
}

// ---------------------------------------------------------------------------
// 1) prep: blocks 0..127 = weight conversion; blocks 128.. = x transpose.
// ---------------------------------------------------------------------------
__global__ __launch_bounds__(256) void prep_kernel(
    const float* __restrict__ x,
    const float* __restrict__ Wq, const float* __restrict__ Wk,
    const float* __restrict__ Wv, const float* __restrict__ Wo,
    u16* __restrict__ Wb, u16* __restrict__ xt)
{
    const int blk = (int)blockIdx.x;
    const int t = (int)threadIdx.x;
    if (blk < 128) {
        const int id = blk * 256 + t;
        const int base = id * 8;
        const int o = base >> 8, c = base & 255;
        const int sel = o >> 8, ol = o & 255;
        const float* src = (sel == 0) ? Wq : (sel == 1) ? Wk : (sel == 2) ? Wv : Wo;
        const float sc = (sel == 0) ? SCALE_LOG2 : 1.0f;
        const float4 a = *(const float4*)&src[(size_t)ol * 256 + c];
        const float4 b = *(const float4*)&src[(size_t)ol * 256 + c + 4];
        u16x8 r;
        r[0]=f2bf(a.x*sc); r[1]=f2bf(a.y*sc); r[2]=f2bf(a.z*sc); r[3]=f2bf(a.w*sc);
        r[4]=f2bf(b.x*sc); r[5]=f2bf(b.y*sc); r[6]=f2bf(b.z*sc); r[7]=f2bf(b.w*sc);
        *(u16x8*)&Wb[(size_t)o * 256 + c] = r;
        return;
    }
    const int bx = blk - 128;           // 0..1535
    const int nt = bx & 31, ct = (bx >> 5) & 3, bi = bx >> 7;
    const int b = bi / 3, i = bi % 3;
    const int n0 = nt * 64, c0 = ct * 64;

    __shared__ u16 tile[64][72];

    const int n_l = t & 63;
#pragma unroll
    for (int it = 0; it < 16; ++it) {
        const int c_l = (t >> 6) + it * 4;
        tile[n_l][c_l] =
            f2bf(x[(((size_t)(b * 256 + c0 + c_l)) * 3 + i) * Nc + n0 + n_l]);
    }
    __syncthreads();
#pragma unroll
    for (int it = 0; it < 2; ++it) {
        const int idx = t + it * 256;
        const int nn = idx >> 3, part = idx & 7;
        *(u16x8*)&xt[((size_t)bi * Nc + n0 + nn) * 256 + c0 + part * 8] =
            *(const u16x8*)&tile[nn][part * 8];
    }
}

// ---------------------------------------------------------------------------
// 2) QKV GEMM (128x128 tile, 4 waves)
// ---------------------------------------------------------------------------
__global__ __launch_bounds__(256) void qkv_gemm_kernel(
    const u16* __restrict__ xt, const u16* __restrict__ wb,
    u16* __restrict__ Qt, u16* __restrict__ Kt, u16* __restrict__ Vf)
{
    const int nt = blockIdx.x;
    const int wy = blockIdx.y;
    const int bi = blockIdx.z;
    const int b = bi / 3, i = bi % 3;
    const int wsel = wy >> 1, ot = wy & 1;

    const u16* xs = xt + ((size_t)bi * Nc + nt * 128) * 256;
    const u16* ws = wb + (size_t)(wsel * 256 + ot * 128) * 256;

    __shared__ u16 xl[128][40];
    __shared__ u16 wl[128][40];

    const int t = (int)threadIdx.x;
    const int wv = t >> 6, lane = t & 63;
    const int g = lane >> 4, c16 = lane & 15;
    const int wr = wv >> 1, wc = wv & 1;

    f32x4 acc[4][4];
#pragma unroll
    for (int mi = 0; mi < 4; ++mi)
#pragma unroll
        for (int ni = 0; ni < 4; ++ni)
#pragma unroll
            for (int r = 0; r < 4; ++r) acc[mi][ni][r] = 0.f;

    for (int ks = 0; ks < 8; ++ks) {
        __syncthreads();
#pragma unroll
        for (int it = 0; it < 2; ++it) {
            const int idx = t + it * 256;
            const int row = idx >> 2, part = idx & 3;
            *(u16x8*)&xl[row][part * 8] =
                *(const u16x8*)&xs[(size_t)row * 256 + ks * 32 + part * 8];
            *(u16x8*)&wl[row][part * 8] =
                *(const u16x8*)&ws[(size_t)row * 256 + ks * 32 + part * 8];
        }
        __syncthreads();

        s16x8 af[4], bf[4];
        if (wsel < 2) {
#pragma unroll
            for (int mi = 0; mi < 4; ++mi) af[mi] = *(const s16x8*)&xl[wr*64 + mi*16 + c16][g*8];
#pragma unroll
            for (int ni = 0; ni < 4; ++ni) bf[ni] = *(const s16x8*)&wl[wc*64 + ni*16 + c16][g*8];
        } else {
#pragma unroll
            for (int mi = 0; mi < 4; ++mi) af[mi] = *(const s16x8*)&wl[wr*64 + mi*16 + c16][g*8];
#pragma unroll
            for (int ni = 0; ni < 4; ++ni) bf[ni] = *(const s16x8*)&xl[wc*64 + ni*16 + c16][g*8];
        }
#pragma unroll
        for (int mi = 0; mi < 4; ++mi)
#pragma unroll
            for (int ni = 0; ni < 4; ++ni)
                acc[mi][ni] = __builtin_amdgcn_mfma_f32_16x16x32_bf16(
                    af[mi], bf[ni], acc[mi][ni], 0, 0, 0);
    }

    if (wsel < 2) {
        u16* dst = wsel ? Kt : Qt;
#pragma unroll
        for (int mi = 0; mi < 4; ++mi)
#pragma unroll
            for (int ni = 0; ni < 4; ++ni) {
                const int o = ot * 128 + wc * 64 + ni * 16 + c16;
                const int h = o >> 5, cw = o & 31;
#pragma unroll
                for (int r = 0; r < 4; ++r) {
                    const int n = nt * 128 + wr * 64 + mi * 16 + g * 4 + r;
                    dst[((size_t)(b * 8 + h) * Nc + n) * Fc + i * 32 + cw] =
                        f2bf(acc[mi][ni][r]);
                }
            }
    } else {
#pragma unroll
        for (int mi = 0; mi < 4; ++mi)
#pragma unroll
            for (int ni = 0; ni < 4; ++ni) {
                const int n = nt * 128 + wc * 64 + ni * 16 + c16;
#pragma unroll
                for (int r = 0; r < 4; ++r) {
                    const int o = ot * 128 + wr * 64 + mi * 16 + g * 4 + r;
                    const int h = o >> 5, cw = o & 31;
                    Vf[((size_t)(b * 8 + h) * Fc + i * 32 + cw) * Nc + n] =
                        f2bf(acc[mi][ni][r]);
                }
            }
    }
}

// ---------------------------------------------------------------------------
// 3) attention: r11 pipelined split-K structure + K/V LDS XOR-swizzle.
//    Swizzle: 16B-unit index ^= (row>>3)&3 on BOTH staging write and
//    fragment read (K rows pitch 52 dwords and V rows pitch 20 dwords both
//    alias banks with period 8 rows; the XOR offsets row-groups 0/8/16/24).
// ---------------------------------------------------------------------------
__global__ __launch_bounds__(256) void attn_mfma_kernel(
    const u16* __restrict__ Qt, const u16* __restrict__ Kt,
    const u16* __restrict__ Vf, u16* __restrict__ obt, float* __restrict__ lP)
{
    // XCD-aware swizzle: 1024 blocks, 128 per XCD
    const int bid = (int)blockIdx.x;
    const int lid = (bid & 7) * 128 + (bid >> 3);
    const int bh   = lid >> 5;
    const int r5   = lid & 31;
    const int qt   = r5 >> 1;        // 0..15
    const int half = r5 & 1;         // key half

    const int t_   = (int)threadIdx.x;
    const int wq   = t_ >> 6;
    const int lane = t_ & 63;
    const int ql   = lane & 31;      // query col / K,V A-frag row
    const int hi   = lane >> 5;
    const int swz  = (ql >> 3) & 3;  // row-group XOR key for K and V reads

    __shared__ u16 sbuf[3 * SBUF];   // 43008 B

    const int qb = qt * 128 + wq * 32;
    const int k0 = half * 1024;

    // Q B-frags
    s16x8 bq[6];
#pragma unroll
    for (int s6 = 0; s6 < 6; ++s6)
        bq[s6] = *(const s16x8*)&Qt[((size_t)bh * Nc + qb + ql) * Fc + s6 * 16 + hi * 8];

    // staging: 3x 16B chunks per thread per 32-key tile (swizzled dst)
    const u16* g_cur[3]; int g_str[3], g_dst[3];
#pragma unroll
    for (int it = 0; it < 3; ++it) {
        const int c = t_ + it * 256;
        if (c < 384) {
            const int row = c / 12, part = c - row * 12;
            g_cur[it] = Kt + ((size_t)bh * Nc + k0 + row) * Fc + part * 8;
            g_str[it] = 32 * Fc;
            g_dst[it] = row * KP + (part ^ ((row >> 3) & 3)) * 8;
        } else {
            const int c2 = c - 384, f = c2 >> 2, part = c2 & 3;
            g_cur[it] = Vf + ((size_t)bh * Fc + f) * Nc + k0 + part * 8;
            g_str[it] = 32;
            g_dst[it] = VOFF + f * VP + (part ^ ((f >> 3) & 3)) * 8;
        }
    }

    f32x16 acc[3];
#pragma unroll
    for (int ft = 0; ft < 3; ++ft)
#pragma unroll
        for (int r = 0; r < 16; ++r) acc[ft][r] = 0.f;
    float lacc[8];
#pragma unroll
    for (int r = 0; r < 8; ++r) lacc[r] = 0.f;

    u16* b0 = sbuf;
    u16* b1 = sbuf + SBUF;
    u16* b2 = sbuf + 2 * SBUF;

    // ---- prologue: tile0 -> b0; tile1 -> b1; tile2 -> regs; QK(0) -> svE
    u16x8 sreg[3];
#pragma unroll
    for (int it = 0; it < 3; ++it) { sreg[it] = *(const u16x8*)g_cur[it]; g_cur[it] += g_str[it]; }
#pragma unroll
    for (int it = 0; it < 3; ++it) *(u16x8*)&b0[g_dst[it]] = sreg[it];
#pragma unroll
    for (int it = 0; it < 3; ++it) { sreg[it] = *(const u16x8*)g_cur[it]; g_cur[it] += g_str[it]; }
    __syncthreads();                               // tile0 visible

    f32x16 svE, svO;
#pragma unroll
    for (int r = 0; r < 16; ++r) svE[r] = 0.f;
#pragma unroll
    for (int s6 = 0; s6 < 6; ++s6) {
        const s16x8 ka = *(const s16x8*)&b0[ql * KP + ((s6 * 2 + hi) ^ swz) * 8];
        svE = __builtin_amdgcn_mfma_f32_32x32x16_bf16(ka, bq[s6], svE, 0, 0, 0);
    }
#pragma unroll
    for (int it = 0; it < 3; ++it) *(u16x8*)&b1[g_dst[it]] = sreg[it];   // tile1
#pragma unroll
    for (int it = 0; it < 3; ++it) { sreg[it] = *(const u16x8*)g_cur[it]; g_cur[it] += g_str[it]; } // tile2
    __syncthreads();                               // tile1 visible

    u16 *bA = b0, *bB = b1, *bC = b2;

    auto body = [&](int t, f32x16& SC, f32x16& SN) {
        // 1) QK(t+1) from bB (independent of softmax(t))
        if (t < 31) {
#pragma unroll
            for (int r = 0; r < 16; ++r) SN[r] = 0.f;
#pragma unroll
            for (int s6 = 0; s6 < 6; ++s6) {
                const s16x8 ka = *(const s16x8*)&bB[ql * KP + ((s6 * 2 + hi) ^ swz) * 8];
                SN = __builtin_amdgcn_mfma_f32_32x32x16_bf16(ka, bq[s6], SN, 0, 0, 0);
            }
        }
        // 2) write tile t+2 (regs) -> bC
        if (t < 30) {
#pragma unroll
            for (int it = 0; it < 3; ++it) *(u16x8*)&bC[g_dst[it]] = sreg[it];
        }
        // 3) issue global loads for tile t+3
        if (t < 29) {
#pragma unroll
            for (int it = 0; it < 3; ++it) { sreg[it] = *(const u16x8*)g_cur[it]; g_cur[it] += g_str[it]; }
        }

        // 4) max-free softmax(t): P = 2^S
#pragma unroll
        for (int r = 0; r < 16; ++r) SC[r] = fast_exp2(SC[r]);
#pragma unroll
        for (int r = 0; r < 8; ++r) lacc[r] += SC[r] + SC[r + 8];

        // pack P -> bf16 B-frags
        u32 pk8[8];
#pragma unroll
        for (int j = 0; j < 8; ++j)
            asm("v_cvt_pk_bf16_f32 %0, %1, %2" : "=v"(pk8[j]) : "v"(SC[2*j]), "v"(SC[2*j+1]));
        asm volatile("v_permlane32_swap_b32 %0, %1" : "+v"(pk8[0]), "+v"(pk8[2]));
        asm volatile("v_permlane32_swap_b32 %0, %1" : "+v"(pk8[1]), "+v"(pk8[3]));
        asm volatile("v_permlane32_swap_b32 %0, %1" : "+v"(pk8[4]), "+v"(pk8[6]));
        asm volatile("v_permlane32_swap_b32 %0, %1" : "+v"(pk8[5]), "+v"(pk8[7]));
        union U { u32 w[4]; s16x8 v; } pb0, pb1;
        pb0.w[0]=pk8[0]; pb0.w[1]=pk8[1]; pb0.w[2]=pk8[2]; pb0.w[3]=pk8[3];
        pb1.w[0]=pk8[4]; pb1.w[1]=pk8[5]; pb1.w[2]=pk8[6]; pb1.w[3]=pk8[7];

        // 5) PV(t): V from bA (swizzled reads)
#pragma unroll
        for (int ft = 0; ft < 3; ++ft) {
            const s16x8 va0 = *(const s16x8*)&bA[VOFF + (ft * 32 + ql) * VP + (hi ^ swz) * 8];
            acc[ft] = __builtin_amdgcn_mfma_f32_32x32x16_bf16(va0, pb0.v, acc[ft], 0, 0, 0);
            const s16x8 va1 = *(const s16x8*)&bA[VOFF + (ft * 32 + ql) * VP + ((2 + hi) ^ swz) * 8];
            acc[ft] = __builtin_amdgcn_mfma_f32_32x32x16_bf16(va1, pb1.v, acc[ft], 0, 0, 0);
        }

        // 6) barrier: tile t+2 writes complete; bA free for reuse next iter
        if (t < 31) __syncthreads();
    };

    for (int tb = 0; tb < 16; ++tb) {
        body(2 * tb, svE, svO);
        { u16* tmp = bA; bA = bB; bB = bC; bC = tmp; }
        body(2 * tb + 1, svO, svE);
        { u16* tmp = bA; bA = bB; bB = bC; bC = tmp; }
    }

    // ---- epilogue: reduce l, store l, LDS transpose, token-major partials
    float l4[4];
#pragma unroll
    for (int r = 0; r < 4; ++r) l4[r] = lacc[r] + lacc[r + 4];
    float l_s = (l4[0] + l4[2]) + (l4[1] + l4[3]);
    l_s += __shfl_xor(l_s, 32);
    const float inv = 1.f / l_s;
    if (hi == 0)
        lP[((size_t)half * 32 + bh) * Nc + qb + ql] = l_s;

    __syncthreads();                                // all PV reads done
    u16* ot = sbuf + wq * 3328;                     // 32 rows x pitch 104
#pragma unroll
    for (int ft = 0; ft < 3; ++ft)
#pragma unroll
        for (int r = 0; r < 16; ++r) {
            const int frow = (r & 3) + 8 * (r >> 2) + 4 * hi;
            ot[ql * 104 + ft * 32 + frow] = f2bf(acc[ft][r] * inv);
        }
    __syncthreads();

    u16x8 v6[6];
#pragma unroll
    for (int j = 0; j < 6; ++j)
        v6[j] = *(const u16x8*)&ot[ql * 104 + hi * 48 + j * 8];

    const int n = qb + ql;
    const int b_ = bh >> 3, h_ = bh & 7;
    const size_t base0 = (((size_t)half * 12 + b_ * 3 + 0) * Nc + n) * 256 + h_ * 32;
    const size_t base1 = (((size_t)half * 12 + b_ * 3 + 1) * Nc + n) * 256 + h_ * 32;
    const size_t base2 = (((size_t)half * 12 + b_ * 3 + 2) * Nc + n) * 256 + h_ * 32;
    if (hi == 0) {   // f 0..47: i=0 cw0..31, i=1 cw0..15
        *(u16x8*)&obt[base0 +  0] = v6[0];
        *(u16x8*)&obt[base0 +  8] = v6[1];
        *(u16x8*)&obt[base0 + 16] = v6[2];
        *(u16x8*)&obt[base0 + 24] = v6[3];
        *(u16x8*)&obt[base1 +  0] = v6[4];
        *(u16x8*)&obt[base1 +  8] = v6[5];
    } else {         // f 48..95: i=1 cw16..31, i=2 cw0..31
        *(u16x8*)&obt[base1 + 16] = v6[0];
        *(u16x8*)&obt[base1 + 24] = v6[1];
        *(u16x8*)&obt[base2 +  0] = v6[2];
        *(u16x8*)&obt[base2 +  8] = v6[3];
        *(u16x8*)&obt[base2 + 16] = v6[4];
        *(u16x8*)&obt[base2 + 24] = v6[5];
    }
}

// ---------------------------------------------------------------------------
// 4) out GEMM + residual, with fused split-K combine in the staging:
//    al[n][c] = w0*obt0 + (1-w0)*obt1, w0 = l0/(l0+l1); head h = ks.
// ---------------------------------------------------------------------------
__global__ __launch_bounds__(256) void out_gemm_kernel(
    const u16* __restrict__ obt, const float* __restrict__ lP,
    const u16* __restrict__ wb, const float* __restrict__ x,
    float* __restrict__ out)
{
    const int nt = blockIdx.x, ot = blockIdx.y, bi = blockIdx.z;
    const int b = bi / 3, i = bi % 3;

    const u16* p0 = obt + ((size_t)bi * Nc) * 256;            // half 0
    const u16* p1 = obt + (((size_t)12 + bi) * Nc) * 256;     // half 1
    const u16* ws = wb + (size_t)(768 + ot * 128) * 256;

    __shared__ u16 al[128][40];
    __shared__ u16 wl[128][40];

    const int t = (int)threadIdx.x;
    const int wv = t >> 6, lane = t & 63;
    const int g = lane >> 4, c16 = lane & 15;
    const int wr = wv >> 1, wc = wv & 1;

    f32x4 acc[4][4];
#pragma unroll
    for (int mi = 0; mi < 4; ++mi)
#pragma unroll
        for (int ni = 0; ni < 4; ++ni)
#pragma unroll
            for (int r = 0; r < 4; ++r) acc[mi][ni][r] = 0.f;

    for (int ks = 0; ks < 8; ++ks) {
        __syncthreads();
#pragma unroll
        for (int it = 0; it < 2; ++it) {
            const int idx = t + it * 256;
            const int row = idx >> 2, part = idx & 3;
            const int n = nt * 128 + row;
            const float l0 = lP[((size_t)(b * 8 + ks)) * Nc + n];
            const float l1 = lP[((size_t)(32 + b * 8 + ks)) * Nc + n];
            const float w0 = l0 / (l0 + l1);
            const float w1 = 1.f - w0;
            const u16x8 a0 = *(const u16x8*)&p0[(size_t)n * 256 + ks * 32 + part * 8];
            const u16x8 a1 = *(const u16x8*)&p1[(size_t)n * 256 + ks * 32 + part * 8];
            u16x8 rr;
#pragma unroll
            for (int j = 0; j < 8; ++j)
                rr[j] = f2bf(bf2f(a0[j]) * w0 + bf2f(a1[j]) * w1);
            *(u16x8*)&al[row][part * 8] = rr;
            *(u16x8*)&wl[row][part * 8] =
                *(const u16x8*)&ws[(size_t)row * 256 + ks * 32 + part * 8];
        }
        __syncthreads();

        s16x8 af[4], bf[4];
#pragma unroll
        for (int mi = 0; mi < 4; ++mi) af[mi] = *(const s16x8*)&wl[wr*64 + mi*16 + c16][g*8];
#pragma unroll
        for (int ni = 0; ni < 4; ++ni) bf[ni] = *(const s16x8*)&al[wc*64 + ni*16 + c16][g*8];
#pragma unroll
        for (int mi = 0; mi < 4; ++mi)
#pragma unroll
            for (int ni = 0; ni < 4; ++ni)
                acc[mi][ni] = __builtin_amdgcn_mfma_f32_16x16x32_bf16(
                    af[mi], bf[ni], acc[mi][ni], 0, 0, 0);
    }

#pragma unroll
    for (int mi = 0; mi < 4; ++mi)
#pragma unroll
        for (int ni = 0; ni < 4; ++ni) {
            const int n = nt * 128 + wc * 64 + ni * 16 + c16;
#pragma unroll
            for (int r = 0; r < 4; ++r) {
                const int o = ot * 128 + wr * 64 + mi * 16 + g * 4 + r;
                const size_t idx = ((size_t)(b * 256 + o) * 3 + i) * Nc + n;
                out[idx] = x[idx] + acc[mi][ni][r];
            }
        }
}

// ---------------------------------------------------------------------------
extern "C" void kernel_launch(void* const* d_in, const int* in_sizes, int n_in,
                              void* d_out, int out_size, void* d_ws, size_t ws_size,
                              hipStream_t stream) {
    const float* x  = (const float*)d_in[0];
    const float* Wq = (const float*)d_in[1];
    const float* Wk = (const float*)d_in[2];
    const float* Wv = (const float*)d_in[3];
    const float* Wo = (const float*)d_in[4];
    float* out = (float*)d_out;

    const size_t E = (size_t)32 * Fc * Nc;       // 6,291,456 u16
    u16* xt  = (u16*)d_ws;                        // E
    u16* wbw = xt + E;                            // 262144
    u16* qt  = wbw + 262144;                      // E
    u16* kt  = qt + E;                            // E
    u16* vf  = kt + E;                            // E
    u16* obt = vf + E;                            // 2*E (token-major partials)
    float* lP = (float*)(obt + 2 * E);            // 131072 floats

    dim3 blk(256);
    prep_kernel     <<<dim3(128 + 1536), blk, 0, stream>>>(x, Wq, Wk, Wv, Wo, wbw, xt);
    qkv_gemm_kernel <<<dim3(16, 6, 12),  blk, 0, stream>>>(xt, wbw, qt, kt, vf);
    attn_mfma_kernel<<<dim3(1024),       blk, 0, stream>>>(qt, kt, vf, obt, lP);
    out_gemm_kernel <<<dim3(16, 2, 12),  blk, 0, stream>>>(obt, lP, wbw, x, out);
}

// Round 14
// 116.129 us; speedup vs baseline: 1.6545x; 1.2934x over previous
//
#include <hip/hip_runtime.h>
#include <hip/hip_bf16.h>
#include <cmath>

// VNAttention MI355X: B=4, C=256, N=2048, H=8, HD=32, F=96, BH=32
// f-enumeration: f = i*32 + cw
// Pipeline:
//   1) prep     : wconv (Wq*SCALE_LOG2,Wk,Wv,Wo -> bf16) + xt transpose, merged
//   2) qkv_gemm : Qt,Kt token-major [bh][n][96]; Vf feature-major [bh][96][n]
//   3) attn     : r11 verbatim — swapped-QK^T 32x32 MFMA, KVBLK=32, triple-
//                 buffered QK(t+1)-ahead pipeline, max-free softmax, split-K=2.
//                 (r13 swizzle reverted: wave64 b128 is bank-floor-limited;
//                 the XOR couldn't change bank residues and made it worse.)
//   4) out_gemm : split-K combine (lerp by l0/(l0+l1)) fused into staging.

typedef unsigned short u16;
typedef unsigned int   u32;
typedef u16   u16x8  __attribute__((ext_vector_type(8)));
typedef short s16x8  __attribute__((ext_vector_type(8)));
typedef float f32x4  __attribute__((ext_vector_type(4)));
typedef float f32x16 __attribute__((ext_vector_type(16)));

namespace {
constexpr int Nc = 2048, Fc = 96;
constexpr float SCALE_LOG2 = 0.17677669529663687f * 1.4426950408889634f;
// attn LDS geometry (u16 units): 32-key tiles, triple-buffered
constexpr int KP = 104;              // K row pitch (32 rows x 96 f)
constexpr int VP = 40;               // V row pitch (96 rows x 32 keys)
constexpr int VOFF = 32 * KP;        // 3328
constexpr int SBUF = VOFF + 96 * VP; // 7168 u16 = 14336 B per buffer
}

__device__ inline float fast_exp2(float x) {
#if __has_builtin(__builtin_amdgcn_exp2f)
    return __builtin_amdgcn_exp2f(x);
#else
    return exp2f(x);
#endif
}

__device__ inline u16 f2bf(float x) {   // RNE f32 -> bf16 bits
    union { float f; unsigned u; } v; v.f = x;
    unsigned r = v.u + 0x7FFFu + ((v.u >> 16) & 1u);
    return (u16)(r >> 16);
}

__device__ inline float bf2f(u16 x) {
    union { unsigned u; float f; } v; v.u = ((unsigned)x) << 16; return v.f;
}

// ---------------------------------------------------------------------------
// 1) prep: blocks 0..127 = weight conversion; blocks 128.. = x transpose.
// ---------------------------------------------------------------------------
__global__ __launch_bounds__(256) void prep_kernel(
    const float* __restrict__ x,
    const float* __restrict__ Wq, const float* __restrict__ Wk,
    const float* __restrict__ Wv, const float* __restrict__ Wo,
    u16* __restrict__ Wb, u16* __restrict__ xt)
{
    const int blk = (int)blockIdx.x;
    const int t = (int)threadIdx.x;
    if (blk < 128) {
        const int id = blk * 256 + t;
        const int base = id * 8;
        const int o = base >> 8, c = base & 255;
        const int sel = o >> 8, ol = o & 255;
        const float* src = (sel == 0) ? Wq : (sel == 1) ? Wk : (sel == 2) ? Wv : Wo;
        const float sc = (sel == 0) ? SCALE_LOG2 : 1.0f;
        const float4 a = *(const float4*)&src[(size_t)ol * 256 + c];
        const float4 b = *(const float4*)&src[(size_t)ol * 256 + c + 4];
        u16x8 r;
        r[0]=f2bf(a.x*sc); r[1]=f2bf(a.y*sc); r[2]=f2bf(a.z*sc); r[3]=f2bf(a.w*sc);
        r[4]=f2bf(b.x*sc); r[5]=f2bf(b.y*sc); r[6]=f2bf(b.z*sc); r[7]=f2bf(b.w*sc);
        *(u16x8*)&Wb[(size_t)o * 256 + c] = r;
        return;
    }
    const int bx = blk - 128;           // 0..1535
    const int nt = bx & 31, ct = (bx >> 5) & 3, bi = bx >> 7;
    const int b = bi / 3, i = bi % 3;
    const int n0 = nt * 64, c0 = ct * 64;

    __shared__ u16 tile[64][72];

    const int n_l = t & 63;
#pragma unroll
    for (int it = 0; it < 16; ++it) {
        const int c_l = (t >> 6) + it * 4;
        tile[n_l][c_l] =
            f2bf(x[(((size_t)(b * 256 + c0 + c_l)) * 3 + i) * Nc + n0 + n_l]);
    }
    __syncthreads();
#pragma unroll
    for (int it = 0; it < 2; ++it) {
        const int idx = t + it * 256;
        const int nn = idx >> 3, part = idx & 7;
        *(u16x8*)&xt[((size_t)bi * Nc + n0 + nn) * 256 + c0 + part * 8] =
            *(const u16x8*)&tile[nn][part * 8];
    }
}

// ---------------------------------------------------------------------------
// 2) QKV GEMM (128x128 tile, 4 waves)
// ---------------------------------------------------------------------------
__global__ __launch_bounds__(256) void qkv_gemm_kernel(
    const u16* __restrict__ xt, const u16* __restrict__ wb,
    u16* __restrict__ Qt, u16* __restrict__ Kt, u16* __restrict__ Vf)
{
    const int nt = blockIdx.x;
    const int wy = blockIdx.y;
    const int bi = blockIdx.z;
    const int b = bi / 3, i = bi % 3;
    const int wsel = wy >> 1, ot = wy & 1;

    const u16* xs = xt + ((size_t)bi * Nc + nt * 128) * 256;
    const u16* ws = wb + (size_t)(wsel * 256 + ot * 128) * 256;

    __shared__ u16 xl[128][40];
    __shared__ u16 wl[128][40];

    const int t = (int)threadIdx.x;
    const int wv = t >> 6, lane = t & 63;
    const int g = lane >> 4, c16 = lane & 15;
    const int wr = wv >> 1, wc = wv & 1;

    f32x4 acc[4][4];
#pragma unroll
    for (int mi = 0; mi < 4; ++mi)
#pragma unroll
        for (int ni = 0; ni < 4; ++ni)
#pragma unroll
            for (int r = 0; r < 4; ++r) acc[mi][ni][r] = 0.f;

    for (int ks = 0; ks < 8; ++ks) {
        __syncthreads();
#pragma unroll
        for (int it = 0; it < 2; ++it) {
            const int idx = t + it * 256;
            const int row = idx >> 2, part = idx & 3;
            *(u16x8*)&xl[row][part * 8] =
                *(const u16x8*)&xs[(size_t)row * 256 + ks * 32 + part * 8];
            *(u16x8*)&wl[row][part * 8] =
                *(const u16x8*)&ws[(size_t)row * 256 + ks * 32 + part * 8];
        }
        __syncthreads();

        s16x8 af[4], bf[4];
        if (wsel < 2) {
#pragma unroll
            for (int mi = 0; mi < 4; ++mi) af[mi] = *(const s16x8*)&xl[wr*64 + mi*16 + c16][g*8];
#pragma unroll
            for (int ni = 0; ni < 4; ++ni) bf[ni] = *(const s16x8*)&wl[wc*64 + ni*16 + c16][g*8];
        } else {
#pragma unroll
            for (int mi = 0; mi < 4; ++mi) af[mi] = *(const s16x8*)&wl[wr*64 + mi*16 + c16][g*8];
#pragma unroll
            for (int ni = 0; ni < 4; ++ni) bf[ni] = *(const s16x8*)&xl[wc*64 + ni*16 + c16][g*8];
        }
#pragma unroll
        for (int mi = 0; mi < 4; ++mi)
#pragma unroll
            for (int ni = 0; ni < 4; ++ni)
                acc[mi][ni] = __builtin_amdgcn_mfma_f32_16x16x32_bf16(
                    af[mi], bf[ni], acc[mi][ni], 0, 0, 0);
    }

    if (wsel < 2) {
        u16* dst = wsel ? Kt : Qt;
#pragma unroll
        for (int mi = 0; mi < 4; ++mi)
#pragma unroll
            for (int ni = 0; ni < 4; ++ni) {
                const int o = ot * 128 + wc * 64 + ni * 16 + c16;
                const int h = o >> 5, cw = o & 31;
#pragma unroll
                for (int r = 0; r < 4; ++r) {
                    const int n = nt * 128 + wr * 64 + mi * 16 + g * 4 + r;
                    dst[((size_t)(b * 8 + h) * Nc + n) * Fc + i * 32 + cw] =
                        f2bf(acc[mi][ni][r]);
                }
            }
    } else {
#pragma unroll
        for (int mi = 0; mi < 4; ++mi)
#pragma unroll
            for (int ni = 0; ni < 4; ++ni) {
                const int n = nt * 128 + wc * 64 + ni * 16 + c16;
#pragma unroll
                for (int r = 0; r < 4; ++r) {
                    const int o = ot * 128 + wr * 64 + mi * 16 + g * 4 + r;
                    const int h = o >> 5, cw = o & 31;
                    Vf[((size_t)(b * 8 + h) * Fc + i * 32 + cw) * Nc + n] =
                        f2bf(acc[mi][ni][r]);
                }
            }
    }
}

// ---------------------------------------------------------------------------
// 3) attention: r11 verbatim (pipelined split-K, plain addressing).
// ---------------------------------------------------------------------------
__global__ __launch_bounds__(256) void attn_mfma_kernel(
    const u16* __restrict__ Qt, const u16* __restrict__ Kt,
    const u16* __restrict__ Vf, u16* __restrict__ obt, float* __restrict__ lP)
{
    // XCD-aware swizzle: 1024 blocks, 128 per XCD
    const int bid = (int)blockIdx.x;
    const int lid = (bid & 7) * 128 + (bid >> 3);
    const int bh   = lid >> 5;
    const int r5   = lid & 31;
    const int qt   = r5 >> 1;        // 0..15
    const int half = r5 & 1;         // key half

    const int t_   = (int)threadIdx.x;
    const int wq   = t_ >> 6;
    const int lane = t_ & 63;
    const int ql   = lane & 31;      // query col (also K/V row for A-frags)
    const int hi   = lane >> 5;

    __shared__ u16 sbuf[3 * SBUF];   // 43008 B

    const int qb = qt * 128 + wq * 32;
    const int k0 = half * 1024;

    // Q B-frags: lane holds Q[qb+ql][16*s6 + 8*hi + j], j=0..7
    s16x8 bq[6];
#pragma unroll
    for (int s6 = 0; s6 < 6; ++s6)
        bq[s6] = *(const s16x8*)&Qt[((size_t)bh * Nc + qb + ql) * Fc + s6 * 16 + hi * 8];

    // staging: 3x 16B chunks per thread per 32-key tile (K: 384, V: 384)
    const u16* g_cur[3]; int g_str[3], g_dst[3];
#pragma unroll
    for (int it = 0; it < 3; ++it) {
        const int c = t_ + it * 256;
        if (c < 384) {
            const int row = c / 12, part = c - row * 12;
            g_cur[it] = Kt + ((size_t)bh * Nc + k0 + row) * Fc + part * 8;
            g_str[it] = 32 * Fc;                    // advance 32 tokens
            g_dst[it] = row * KP + part * 8;
        } else {
            const int c2 = c - 384, f = c2 >> 2, part = c2 & 3;
            g_cur[it] = Vf + ((size_t)bh * Fc + f) * Nc + k0 + part * 8;
            g_str[it] = 32;                         // advance 32 keys
            g_dst[it] = VOFF + f * VP + part * 8;
        }
    }

    f32x16 acc[3];
#pragma unroll
    for (int ft = 0; ft < 3; ++ft)
#pragma unroll
        for (int r = 0; r < 16; ++r) acc[ft][r] = 0.f;
    float lacc[8];
#pragma unroll
    for (int r = 0; r < 8; ++r) lacc[r] = 0.f;

    u16* b0 = sbuf;
    u16* b1 = sbuf + SBUF;
    u16* b2 = sbuf + 2 * SBUF;

    // ---- prologue: tile0 -> b0; tile1 -> b1; tile2 -> regs; QK(0) -> svE
    u16x8 sreg[3];
#pragma unroll
    for (int it = 0; it < 3; ++it) { sreg[it] = *(const u16x8*)g_cur[it]; g_cur[it] += g_str[it]; }
#pragma unroll
    for (int it = 0; it < 3; ++it) *(u16x8*)&b0[g_dst[it]] = sreg[it];
#pragma unroll
    for (int it = 0; it < 3; ++it) { sreg[it] = *(const u16x8*)g_cur[it]; g_cur[it] += g_str[it]; }
    __syncthreads();                               // tile0 visible

    f32x16 svE, svO;
#pragma unroll
    for (int r = 0; r < 16; ++r) svE[r] = 0.f;
#pragma unroll
    for (int s6 = 0; s6 < 6; ++s6) {
        const s16x8 ka = *(const s16x8*)&b0[ql * KP + s6 * 16 + hi * 8];
        svE = __builtin_amdgcn_mfma_f32_32x32x16_bf16(ka, bq[s6], svE, 0, 0, 0);
    }
#pragma unroll
    for (int it = 0; it < 3; ++it) *(u16x8*)&b1[g_dst[it]] = sreg[it];   // tile1
#pragma unroll
    for (int it = 0; it < 3; ++it) { sreg[it] = *(const u16x8*)g_cur[it]; g_cur[it] += g_str[it]; } // tile2
    __syncthreads();                               // tile1 visible

    u16 *bA = b0, *bB = b1, *bC = b2;

    auto body = [&](int t, f32x16& SC, f32x16& SN) {
        // 1) QK(t+1) from bB (independent of softmax(t))
        if (t < 31) {
#pragma unroll
            for (int r = 0; r < 16; ++r) SN[r] = 0.f;
#pragma unroll
            for (int s6 = 0; s6 < 6; ++s6) {
                const s16x8 ka = *(const s16x8*)&bB[ql * KP + s6 * 16 + hi * 8];
                SN = __builtin_amdgcn_mfma_f32_32x32x16_bf16(ka, bq[s6], SN, 0, 0, 0);
            }
        }
        // 2) write tile t+2 (regs) -> bC
        if (t < 30) {
#pragma unroll
            for (int it = 0; it < 3; ++it) *(u16x8*)&bC[g_dst[it]] = sreg[it];
        }
        // 3) issue global loads for tile t+3
        if (t < 29) {
#pragma unroll
            for (int it = 0; it < 3; ++it) { sreg[it] = *(const u16x8*)g_cur[it]; g_cur[it] += g_str[it]; }
        }

        // 4) max-free softmax(t): P = 2^S
#pragma unroll
        for (int r = 0; r < 16; ++r) SC[r] = fast_exp2(SC[r]);
#pragma unroll
        for (int r = 0; r < 8; ++r) lacc[r] += SC[r] + SC[r + 8];

        // pack P -> bf16 B-frags
        u32 pk8[8];
#pragma unroll
        for (int j = 0; j < 8; ++j)
            asm("v_cvt_pk_bf16_f32 %0, %1, %2" : "=v"(pk8[j]) : "v"(SC[2*j]), "v"(SC[2*j+1]));
        asm volatile("v_permlane32_swap_b32 %0, %1" : "+v"(pk8[0]), "+v"(pk8[2]));
        asm volatile("v_permlane32_swap_b32 %0, %1" : "+v"(pk8[1]), "+v"(pk8[3]));
        asm volatile("v_permlane32_swap_b32 %0, %1" : "+v"(pk8[4]), "+v"(pk8[6]));
        asm volatile("v_permlane32_swap_b32 %0, %1" : "+v"(pk8[5]), "+v"(pk8[7]));
        union U { u32 w[4]; s16x8 v; } pb0, pb1;
        pb0.w[0]=pk8[0]; pb0.w[1]=pk8[1]; pb0.w[2]=pk8[2]; pb0.w[3]=pk8[3];
        pb1.w[0]=pk8[4]; pb1.w[1]=pk8[5]; pb1.w[2]=pk8[6]; pb1.w[3]=pk8[7];

        // 5) PV(t): V from bA
#pragma unroll
        for (int ft = 0; ft < 3; ++ft) {
            const s16x8 va0 = *(const s16x8*)&bA[VOFF + (ft * 32 + ql) * VP + hi * 8];
            acc[ft] = __builtin_amdgcn_mfma_f32_32x32x16_bf16(va0, pb0.v, acc[ft], 0, 0, 0);
            const s16x8 va1 = *(const s16x8*)&bA[VOFF + (ft * 32 + ql) * VP + 16 + hi * 8];
            acc[ft] = __builtin_amdgcn_mfma_f32_32x32x16_bf16(va1, pb1.v, acc[ft], 0, 0, 0);
        }

        // 6) barrier: tile t+2 writes complete; bA free for reuse next iter
        if (t < 31) __syncthreads();
    };

    for (int tb = 0; tb < 16; ++tb) {
        body(2 * tb, svE, svO);
        { u16* tmp = bA; bA = bB; bB = bC; bC = tmp; }
        body(2 * tb + 1, svO, svE);
        { u16* tmp = bA; bA = bB; bB = bC; bC = tmp; }
    }

    // ---- epilogue: reduce l, store l, LDS transpose, token-major partials
    float l4[4];
#pragma unroll
    for (int r = 0; r < 4; ++r) l4[r] = lacc[r] + lacc[r + 4];
    float l_s = (l4[0] + l4[2]) + (l4[1] + l4[3]);
    l_s += __shfl_xor(l_s, 32);
    const float inv = 1.f / l_s;
    if (hi == 0)
        lP[((size_t)half * 32 + bh) * Nc + qb + ql] = l_s;

    __syncthreads();                                // all PV reads done
    u16* ot = sbuf + wq * 3328;                     // 32 rows x pitch 104
#pragma unroll
    for (int ft = 0; ft < 3; ++ft)
#pragma unroll
        for (int r = 0; r < 16; ++r) {
            const int frow = (r & 3) + 8 * (r >> 2) + 4 * hi;
            ot[ql * 104 + ft * 32 + frow] = f2bf(acc[ft][r] * inv);
        }
    __syncthreads();

    u16x8 v6[6];
#pragma unroll
    for (int j = 0; j < 6; ++j)
        v6[j] = *(const u16x8*)&ot[ql * 104 + hi * 48 + j * 8];

    const int n = qb + ql;
    const int b_ = bh >> 3, h_ = bh & 7;
    const size_t base0 = (((size_t)half * 12 + b_ * 3 + 0) * Nc + n) * 256 + h_ * 32;
    const size_t base1 = (((size_t)half * 12 + b_ * 3 + 1) * Nc + n) * 256 + h_ * 32;
    const size_t base2 = (((size_t)half * 12 + b_ * 3 + 2) * Nc + n) * 256 + h_ * 32;
    if (hi == 0) {   // f 0..47: i=0 cw0..31, i=1 cw0..15
        *(u16x8*)&obt[base0 +  0] = v6[0];
        *(u16x8*)&obt[base0 +  8] = v6[1];
        *(u16x8*)&obt[base0 + 16] = v6[2];
        *(u16x8*)&obt[base0 + 24] = v6[3];
        *(u16x8*)&obt[base1 +  0] = v6[4];
        *(u16x8*)&obt[base1 +  8] = v6[5];
    } else {         // f 48..95: i=1 cw16..31, i=2 cw0..31
        *(u16x8*)&obt[base1 + 16] = v6[0];
        *(u16x8*)&obt[base1 + 24] = v6[1];
        *(u16x8*)&obt[base2 +  0] = v6[2];
        *(u16x8*)&obt[base2 +  8] = v6[3];
        *(u16x8*)&obt[base2 + 16] = v6[4];
        *(u16x8*)&obt[base2 + 24] = v6[5];
    }
}

// ---------------------------------------------------------------------------
// 4) out GEMM + residual, with fused split-K combine in the staging:
//    al[n][c] = w0*obt0 + (1-w0)*obt1, w0 = l0/(l0+l1); head h = ks.
// ---------------------------------------------------------------------------
__global__ __launch_bounds__(256) void out_gemm_kernel(
    const u16* __restrict__ obt, const float* __restrict__ lP,
    const u16* __restrict__ wb, const float* __restrict__ x,
    float* __restrict__ out)
{
    const int nt = blockIdx.x, ot = blockIdx.y, bi = blockIdx.z;
    const int b = bi / 3, i = bi % 3;

    const u16* p0 = obt + ((size_t)bi * Nc) * 256;            // half 0
    const u16* p1 = obt + (((size_t)12 + bi) * Nc) * 256;     // half 1
    const u16* ws = wb + (size_t)(768 + ot * 128) * 256;

    __shared__ u16 al[128][40];
    __shared__ u16 wl[128][40];

    const int t = (int)threadIdx.x;
    const int wv = t >> 6, lane = t & 63;
    const int g = lane >> 4, c16 = lane & 15;
    const int wr = wv >> 1, wc = wv & 1;

    f32x4 acc[4][4];
#pragma unroll
    for (int mi = 0; mi < 4; ++mi)
#pragma unroll
        for (int ni = 0; ni < 4; ++ni)
#pragma unroll
            for (int r = 0; r < 4; ++r) acc[mi][ni][r] = 0.f;

    for (int ks = 0; ks < 8; ++ks) {
        __syncthreads();
#pragma unroll
        for (int it = 0; it < 2; ++it) {
            const int idx = t + it * 256;
            const int row = idx >> 2, part = idx & 3;
            const int n = nt * 128 + row;
            const float l0 = lP[((size_t)(b * 8 + ks)) * Nc + n];
            const float l1 = lP[((size_t)(32 + b * 8 + ks)) * Nc + n];
            const float w0 = l0 / (l0 + l1);
            const float w1 = 1.f - w0;
            const u16x8 a0 = *(const u16x8*)&p0[(size_t)n * 256 + ks * 32 + part * 8];
            const u16x8 a1 = *(const u16x8*)&p1[(size_t)n * 256 + ks * 32 + part * 8];
            u16x8 rr;
#pragma unroll
            for (int j = 0; j < 8; ++j)
                rr[j] = f2bf(bf2f(a0[j]) * w0 + bf2f(a1[j]) * w1);
            *(u16x8*)&al[row][part * 8] = rr;
            *(u16x8*)&wl[row][part * 8] =
                *(const u16x8*)&ws[(size_t)row * 256 + ks * 32 + part * 8];
        }
        __syncthreads();

        s16x8 af[4], bf[4];
#pragma unroll
        for (int mi = 0; mi < 4; ++mi) af[mi] = *(const s16x8*)&wl[wr*64 + mi*16 + c16][g*8];
#pragma unroll
        for (int ni = 0; ni < 4; ++ni) bf[ni] = *(const s16x8*)&al[wc*64 + ni*16 + c16][g*8];
#pragma unroll
        for (int mi = 0; mi < 4; ++mi)
#pragma unroll
            for (int ni = 0; ni < 4; ++ni)
                acc[mi][ni] = __builtin_amdgcn_mfma_f32_16x16x32_bf16(
                    af[mi], bf[ni], acc[mi][ni], 0, 0, 0);
    }

#pragma unroll
    for (int mi = 0; mi < 4; ++mi)
#pragma unroll
        for (int ni = 0; ni < 4; ++ni) {
            const int n = nt * 128 + wc * 64 + ni * 16 + c16;
#pragma unroll
            for (int r = 0; r < 4; ++r) {
                const int o = ot * 128 + wr * 64 + mi * 16 + g * 4 + r;
                const size_t idx = ((size_t)(b * 256 + o) * 3 + i) * Nc + n;
                out[idx] = x[idx] + acc[mi][ni][r];
            }
        }
}

// ---------------------------------------------------------------------------
extern "C" void kernel_launch(void* const* d_in, const int* in_sizes, int n_in,
                              void* d_out, int out_size, void* d_ws, size_t ws_size,
                              hipStream_t stream) {
    const float* x  = (const float*)d_in[0];
    const float* Wq = (const float*)d_in[1];
    const float* Wk = (const float*)d_in[2];
    const float* Wv = (const float*)d_in[3];
    const float* Wo = (const float*)d_in[4];
    float* out = (float*)d_out;

    const size_t E = (size_t)32 * Fc * Nc;       // 6,291,456 u16
    u16* xt  = (u16*)d_ws;                        // E
    u16* wbw = xt + E;                            // 262144
    u16* qt  = wbw + 262144;                      // E
    u16* kt  = qt + E;                            // E
    u16* vf  = kt + E;                            // E
    u16* obt = vf + E;                            // 2*E (token-major partials)
    float* lP = (float*)(obt + 2 * E);            // 131072 floats

    dim3 blk(256);
    prep_kernel     <<<dim3(128 + 1536), blk, 0, stream>>>(x, Wq, Wk, Wv, Wo, wbw, xt);
    qkv_gemm_kernel <<<dim3(16, 6, 12),  blk, 0, stream>>>(xt, wbw, qt, kt, vf);
    attn_mfma_kernel<<<dim3(1024),       blk, 0, stream>>>(qt, kt, vf, obt, lP);
    out_gemm_kernel <<<dim3(16, 2, 12),  blk, 0, stream>>>(obt, lP, wbw, x, out);
}

// Round 15
// 111.492 us; speedup vs baseline: 1.7233x; 1.0416x over previous
//
#include <hip/hip_runtime.h>
#include <hip/hip_bf16.h>
#include <cmath>

// VNAttention MI355X: B=4, C=256, N=2048, H=8, HD=32, F=96, BH=32
// f-enumeration: f = i*32 + cw
// Pipeline:
//   1) prep     : wconv + xt transpose merged (paired-channel u32 LDS writes)
//   2) qkv_gemm : BK=64 (8 barriers); Qt,Kt token-major; Vf feature-major
//   3) attn     : r11/r14 verbatim — swapped-QK^T 32x32 MFMA, KVBLK=32,
//                 triple-buffered QK(t+1)-ahead pipeline, max-free softmax,
//                 split-K=2. (Structurally pinned at ~71us: chain-bound at
//                 ~2 waves/SIMD; 10 variants tried, all >=68us.)
//   4) out_gemm : BK=64; split-K combine (lerp by l0/(l0+l1)) fused in staging.

typedef unsigned short u16;
typedef unsigned int   u32;
typedef u16   u16x8  __attribute__((ext_vector_type(8)));
typedef short s16x8  __attribute__((ext_vector_type(8)));
typedef float f32x4  __attribute__((ext_vector_type(4)));
typedef float f32x16 __attribute__((ext_vector_type(16)));

namespace {
constexpr int Nc = 2048, Fc = 96;
constexpr float SCALE_LOG2 = 0.17677669529663687f * 1.4426950408889634f;
// attn LDS geometry (u16 units): 32-key tiles, triple-buffered
constexpr int KP = 104;              // K row pitch (32 rows x 96 f)
constexpr int VP = 40;               // V row pitch (96 rows x 32 keys)
constexpr int VOFF = 32 * KP;        // 3328
constexpr int SBUF = VOFF + 96 * VP; // 7168 u16 = 14336 B per buffer
}

__device__ inline float fast_exp2(float x) {
#if __has_builtin(__builtin_amdgcn_exp2f)
    return __builtin_amdgcn_exp2f(x);
#else
    return exp2f(x);
#endif
}

__device__ inline u16 f2bf(float x) {   // RNE f32 -> bf16 bits
    union { float f; unsigned u; } v; v.f = x;
    unsigned r = v.u + 0x7FFFu + ((v.u >> 16) & 1u);
    return (u16)(r >> 16);
}

__device__ inline float bf2f(u16 x) {
    union { unsigned u; float f; } v; v.u = ((unsigned)x) << 16; return v.f;
}

// ---------------------------------------------------------------------------
// 1) prep: blocks 0..127 = weight conversion; blocks 128.. = x transpose.
// ---------------------------------------------------------------------------
__global__ __launch_bounds__(256) void prep_kernel(
    const float* __restrict__ x,
    const float* __restrict__ Wq, const float* __restrict__ Wk,
    const float* __restrict__ Wv, const float* __restrict__ Wo,
    u16* __restrict__ Wb, u16* __restrict__ xt)
{
    const int blk = (int)blockIdx.x;
    const int t = (int)threadIdx.x;
    if (blk < 128) {
        const int id = blk * 256 + t;
        const int base = id * 8;
        const int o = base >> 8, c = base & 255;
        const int sel = o >> 8, ol = o & 255;
        const float* src = (sel == 0) ? Wq : (sel == 1) ? Wk : (sel == 2) ? Wv : Wo;
        const float sc = (sel == 0) ? SCALE_LOG2 : 1.0f;
        const float4 a = *(const float4*)&src[(size_t)ol * 256 + c];
        const float4 b = *(const float4*)&src[(size_t)ol * 256 + c + 4];
        u16x8 r;
        r[0]=f2bf(a.x*sc); r[1]=f2bf(a.y*sc); r[2]=f2bf(a.z*sc); r[3]=f2bf(a.w*sc);
        r[4]=f2bf(b.x*sc); r[5]=f2bf(b.y*sc); r[6]=f2bf(b.z*sc); r[7]=f2bf(b.w*sc);
        *(u16x8*)&Wb[(size_t)o * 256 + c] = r;
        return;
    }
    const int bx = blk - 128;           // 0..1535
    const int nt = bx & 31, ct = (bx >> 5) & 3, bi = bx >> 7;
    const int b = bi / 3, i = bi % 3;
    const int n0 = nt * 64, c0 = ct * 64;

    __shared__ u16 tile[64][72];

    // paired-channel writes: thread covers c0l, c0l+1 -> one u32 LDS write
    const int n_l = t & 63;
#pragma unroll
    for (int it = 0; it < 8; ++it) {
        const int c_l = (t >> 6) * 2 + it * 8;
        const float v0 = x[(((size_t)(b * 256 + c0 + c_l)) * 3 + i) * Nc + n0 + n_l];
        const float v1 = x[(((size_t)(b * 256 + c0 + c_l + 1)) * 3 + i) * Nc + n0 + n_l];
        const u32 pk = (u32)f2bf(v0) | ((u32)f2bf(v1) << 16);
        *(u32*)&tile[n_l][c_l] = pk;
    }
    __syncthreads();
#pragma unroll
    for (int it = 0; it < 2; ++it) {
        const int idx = t + it * 256;
        const int nn = idx >> 3, part = idx & 7;
        *(u16x8*)&xt[((size_t)bi * Nc + n0 + nn) * 256 + c0 + part * 8] =
            *(const u16x8*)&tile[nn][part * 8];
    }
}

// ---------------------------------------------------------------------------
// 2) QKV GEMM (128x128 tile, 4 waves, BK=64: 4 periods, 8 barriers)
// ---------------------------------------------------------------------------
__global__ __launch_bounds__(256) void qkv_gemm_kernel(
    const u16* __restrict__ xt, const u16* __restrict__ wb,
    u16* __restrict__ Qt, u16* __restrict__ Kt, u16* __restrict__ Vf)
{
    const int nt = blockIdx.x;
    const int wy = blockIdx.y;
    const int bi = blockIdx.z;
    const int b = bi / 3, i = bi % 3;
    const int wsel = wy >> 1, ot = wy & 1;

    const u16* xs = xt + ((size_t)bi * Nc + nt * 128) * 256;
    const u16* ws = wb + (size_t)(wsel * 256 + ot * 128) * 256;

    __shared__ u16 xl[128][72];
    __shared__ u16 wl[128][72];

    const int t = (int)threadIdx.x;
    const int wv = t >> 6, lane = t & 63;
    const int g = lane >> 4, c16 = lane & 15;
    const int wr = wv >> 1, wc = wv & 1;

    f32x4 acc[4][4];
#pragma unroll
    for (int mi = 0; mi < 4; ++mi)
#pragma unroll
        for (int ni = 0; ni < 4; ++ni)
#pragma unroll
            for (int r = 0; r < 4; ++r) acc[mi][ni][r] = 0.f;

    for (int ks = 0; ks < 4; ++ks) {
        __syncthreads();
#pragma unroll
        for (int it = 0; it < 4; ++it) {
            const int idx = t + it * 256;
            const int row = idx >> 3, part = idx & 7;
            *(u16x8*)&xl[row][part * 8] =
                *(const u16x8*)&xs[(size_t)row * 256 + ks * 64 + part * 8];
            *(u16x8*)&wl[row][part * 8] =
                *(const u16x8*)&ws[(size_t)row * 256 + ks * 64 + part * 8];
        }
        __syncthreads();

#pragma unroll
        for (int kk = 0; kk < 2; ++kk) {
            s16x8 af[4], bf[4];
            if (wsel < 2) {
#pragma unroll
                for (int mi = 0; mi < 4; ++mi) af[mi] = *(const s16x8*)&xl[wr*64 + mi*16 + c16][kk*32 + g*8];
#pragma unroll
                for (int ni = 0; ni < 4; ++ni) bf[ni] = *(const s16x8*)&wl[wc*64 + ni*16 + c16][kk*32 + g*8];
            } else {
#pragma unroll
                for (int mi = 0; mi < 4; ++mi) af[mi] = *(const s16x8*)&wl[wr*64 + mi*16 + c16][kk*32 + g*8];
#pragma unroll
                for (int ni = 0; ni < 4; ++ni) bf[ni] = *(const s16x8*)&xl[wc*64 + ni*16 + c16][kk*32 + g*8];
            }
#pragma unroll
            for (int mi = 0; mi < 4; ++mi)
#pragma unroll
                for (int ni = 0; ni < 4; ++ni)
                    acc[mi][ni] = __builtin_amdgcn_mfma_f32_16x16x32_bf16(
                        af[mi], bf[ni], acc[mi][ni], 0, 0, 0);
        }
    }

    if (wsel < 2) {
        u16* dst = wsel ? Kt : Qt;
#pragma unroll
        for (int mi = 0; mi < 4; ++mi)
#pragma unroll
            for (int ni = 0; ni < 4; ++ni) {
                const int o = ot * 128 + wc * 64 + ni * 16 + c16;
                const int h = o >> 5, cw = o & 31;
#pragma unroll
                for (int r = 0; r < 4; ++r) {
                    const int n = nt * 128 + wr * 64 + mi * 16 + g * 4 + r;
                    dst[((size_t)(b * 8 + h) * Nc + n) * Fc + i * 32 + cw] =
                        f2bf(acc[mi][ni][r]);
                }
            }
    } else {
#pragma unroll
        for (int mi = 0; mi < 4; ++mi)
#pragma unroll
            for (int ni = 0; ni < 4; ++ni) {
                const int n = nt * 128 + wc * 64 + ni * 16 + c16;
#pragma unroll
                for (int r = 0; r < 4; ++r) {
                    const int o = ot * 128 + wr * 64 + mi * 16 + g * 4 + r;
                    const int h = o >> 5, cw = o & 31;
                    Vf[((size_t)(b * 8 + h) * Fc + i * 32 + cw) * Nc + n] =
                        f2bf(acc[mi][ni][r]);
                }
            }
    }
}

// ---------------------------------------------------------------------------
// 3) attention: r11/r14 verbatim (pipelined split-K, plain addressing).
// ---------------------------------------------------------------------------
__global__ __launch_bounds__(256) void attn_mfma_kernel(
    const u16* __restrict__ Qt, const u16* __restrict__ Kt,
    const u16* __restrict__ Vf, u16* __restrict__ obt, float* __restrict__ lP)
{
    // XCD-aware swizzle: 1024 blocks, 128 per XCD
    const int bid = (int)blockIdx.x;
    const int lid = (bid & 7) * 128 + (bid >> 3);
    const int bh   = lid >> 5;
    const int r5   = lid & 31;
    const int qt   = r5 >> 1;        // 0..15
    const int half = r5 & 1;         // key half

    const int t_   = (int)threadIdx.x;
    const int wq   = t_ >> 6;
    const int lane = t_ & 63;
    const int ql   = lane & 31;      // query col (also K/V row for A-frags)
    const int hi   = lane >> 5;

    __shared__ u16 sbuf[3 * SBUF];   // 43008 B

    const int qb = qt * 128 + wq * 32;
    const int k0 = half * 1024;

    // Q B-frags: lane holds Q[qb+ql][16*s6 + 8*hi + j], j=0..7
    s16x8 bq[6];
#pragma unroll
    for (int s6 = 0; s6 < 6; ++s6)
        bq[s6] = *(const s16x8*)&Qt[((size_t)bh * Nc + qb + ql) * Fc + s6 * 16 + hi * 8];

    // staging: 3x 16B chunks per thread per 32-key tile (K: 384, V: 384)
    const u16* g_cur[3]; int g_str[3], g_dst[3];
#pragma unroll
    for (int it = 0; it < 3; ++it) {
        const int c = t_ + it * 256;
        if (c < 384) {
            const int row = c / 12, part = c - row * 12;
            g_cur[it] = Kt + ((size_t)bh * Nc + k0 + row) * Fc + part * 8;
            g_str[it] = 32 * Fc;                    // advance 32 tokens
            g_dst[it] = row * KP + part * 8;
        } else {
            const int c2 = c - 384, f = c2 >> 2, part = c2 & 3;
            g_cur[it] = Vf + ((size_t)bh * Fc + f) * Nc + k0 + part * 8;
            g_str[it] = 32;                         // advance 32 keys
            g_dst[it] = VOFF + f * VP + part * 8;
        }
    }

    f32x16 acc[3];
#pragma unroll
    for (int ft = 0; ft < 3; ++ft)
#pragma unroll
        for (int r = 0; r < 16; ++r) acc[ft][r] = 0.f;
    float lacc[8];
#pragma unroll
    for (int r = 0; r < 8; ++r) lacc[r] = 0.f;

    u16* b0 = sbuf;
    u16* b1 = sbuf + SBUF;
    u16* b2 = sbuf + 2 * SBUF;

    // ---- prologue: tile0 -> b0; tile1 -> b1; tile2 -> regs; QK(0) -> svE
    u16x8 sreg[3];
#pragma unroll
    for (int it = 0; it < 3; ++it) { sreg[it] = *(const u16x8*)g_cur[it]; g_cur[it] += g_str[it]; }
#pragma unroll
    for (int it = 0; it < 3; ++it) *(u16x8*)&b0[g_dst[it]] = sreg[it];
#pragma unroll
    for (int it = 0; it < 3; ++it) { sreg[it] = *(const u16x8*)g_cur[it]; g_cur[it] += g_str[it]; }
    __syncthreads();                               // tile0 visible

    f32x16 svE, svO;
#pragma unroll
    for (int r = 0; r < 16; ++r) svE[r] = 0.f;
#pragma unroll
    for (int s6 = 0; s6 < 6; ++s6) {
        const s16x8 ka = *(const s16x8*)&b0[ql * KP + s6 * 16 + hi * 8];
        svE = __builtin_amdgcn_mfma_f32_32x32x16_bf16(ka, bq[s6], svE, 0, 0, 0);
    }
#pragma unroll
    for (int it = 0; it < 3; ++it) *(u16x8*)&b1[g_dst[it]] = sreg[it];   // tile1
#pragma unroll
    for (int it = 0; it < 3; ++it) { sreg[it] = *(const u16x8*)g_cur[it]; g_cur[it] += g_str[it]; } // tile2
    __syncthreads();                               // tile1 visible

    u16 *bA = b0, *bB = b1, *bC = b2;

    auto body = [&](int t, f32x16& SC, f32x16& SN) {
        // 1) QK(t+1) from bB (independent of softmax(t))
        if (t < 31) {
#pragma unroll
            for (int r = 0; r < 16; ++r) SN[r] = 0.f;
#pragma unroll
            for (int s6 = 0; s6 < 6; ++s6) {
                const s16x8 ka = *(const s16x8*)&bB[ql * KP + s6 * 16 + hi * 8];
                SN = __builtin_amdgcn_mfma_f32_32x32x16_bf16(ka, bq[s6], SN, 0, 0, 0);
            }
        }
        // 2) write tile t+2 (regs) -> bC
        if (t < 30) {
#pragma unroll
            for (int it = 0; it < 3; ++it) *(u16x8*)&bC[g_dst[it]] = sreg[it];
        }
        // 3) issue global loads for tile t+3
        if (t < 29) {
#pragma unroll
            for (int it = 0; it < 3; ++it) { sreg[it] = *(const u16x8*)g_cur[it]; g_cur[it] += g_str[it]; }
        }

        // 4) max-free softmax(t): P = 2^S
#pragma unroll
        for (int r = 0; r < 16; ++r) SC[r] = fast_exp2(SC[r]);
#pragma unroll
        for (int r = 0; r < 8; ++r) lacc[r] += SC[r] + SC[r + 8];

        // pack P -> bf16 B-frags
        u32 pk8[8];
#pragma unroll
        for (int j = 0; j < 8; ++j)
            asm("v_cvt_pk_bf16_f32 %0, %1, %2" : "=v"(pk8[j]) : "v"(SC[2*j]), "v"(SC[2*j+1]));
        asm volatile("v_permlane32_swap_b32 %0, %1" : "+v"(pk8[0]), "+v"(pk8[2]));
        asm volatile("v_permlane32_swap_b32 %0, %1" : "+v"(pk8[1]), "+v"(pk8[3]));
        asm volatile("v_permlane32_swap_b32 %0, %1" : "+v"(pk8[4]), "+v"(pk8[6]));
        asm volatile("v_permlane32_swap_b32 %0, %1" : "+v"(pk8[5]), "+v"(pk8[7]));
        union U { u32 w[4]; s16x8 v; } pb0, pb1;
        pb0.w[0]=pk8[0]; pb0.w[1]=pk8[1]; pb0.w[2]=pk8[2]; pb0.w[3]=pk8[3];
        pb1.w[0]=pk8[4]; pb1.w[1]=pk8[5]; pb1.w[2]=pk8[6]; pb1.w[3]=pk8[7];

        // 5) PV(t): V from bA
#pragma unroll
        for (int ft = 0; ft < 3; ++ft) {
            const s16x8 va0 = *(const s16x8*)&bA[VOFF + (ft * 32 + ql) * VP + hi * 8];
            acc[ft] = __builtin_amdgcn_mfma_f32_32x32x16_bf16(va0, pb0.v, acc[ft], 0, 0, 0);
            const s16x8 va1 = *(const s16x8*)&bA[VOFF + (ft * 32 + ql) * VP + 16 + hi * 8];
            acc[ft] = __builtin_amdgcn_mfma_f32_32x32x16_bf16(va1, pb1.v, acc[ft], 0, 0, 0);
        }

        // 6) barrier: tile t+2 writes complete; bA free for reuse next iter
        if (t < 31) __syncthreads();
    };

    for (int tb = 0; tb < 16; ++tb) {
        body(2 * tb, svE, svO);
        { u16* tmp = bA; bA = bB; bB = bC; bC = tmp; }
        body(2 * tb + 1, svO, svE);
        { u16* tmp = bA; bA = bB; bB = bC; bC = tmp; }
    }

    // ---- epilogue: reduce l, store l, LDS transpose, token-major partials
    float l4[4];
#pragma unroll
    for (int r = 0; r < 4; ++r) l4[r] = lacc[r] + lacc[r + 4];
    float l_s = (l4[0] + l4[2]) + (l4[1] + l4[3]);
    l_s += __shfl_xor(l_s, 32);
    const float inv = 1.f / l_s;
    if (hi == 0)
        lP[((size_t)half * 32 + bh) * Nc + qb + ql] = l_s;

    __syncthreads();                                // all PV reads done
    u16* ot = sbuf + wq * 3328;                     // 32 rows x pitch 104
#pragma unroll
    for (int ft = 0; ft < 3; ++ft)
#pragma unroll
        for (int r = 0; r < 16; ++r) {
            const int frow = (r & 3) + 8 * (r >> 2) + 4 * hi;
            ot[ql * 104 + ft * 32 + frow] = f2bf(acc[ft][r] * inv);
        }
    __syncthreads();

    u16x8 v6[6];
#pragma unroll
    for (int j = 0; j < 6; ++j)
        v6[j] = *(const u16x8*)&ot[ql * 104 + hi * 48 + j * 8];

    const int n = qb + ql;
    const int b_ = bh >> 3, h_ = bh & 7;
    const size_t base0 = (((size_t)half * 12 + b_ * 3 + 0) * Nc + n) * 256 + h_ * 32;
    const size_t base1 = (((size_t)half * 12 + b_ * 3 + 1) * Nc + n) * 256 + h_ * 32;
    const size_t base2 = (((size_t)half * 12 + b_ * 3 + 2) * Nc + n) * 256 + h_ * 32;
    if (hi == 0) {   // f 0..47: i=0 cw0..31, i=1 cw0..15
        *(u16x8*)&obt[base0 +  0] = v6[0];
        *(u16x8*)&obt[base0 +  8] = v6[1];
        *(u16x8*)&obt[base0 + 16] = v6[2];
        *(u16x8*)&obt[base0 + 24] = v6[3];
        *(u16x8*)&obt[base1 +  0] = v6[4];
        *(u16x8*)&obt[base1 +  8] = v6[5];
    } else {         // f 48..95: i=1 cw16..31, i=2 cw0..31
        *(u16x8*)&obt[base1 + 16] = v6[0];
        *(u16x8*)&obt[base1 + 24] = v6[1];
        *(u16x8*)&obt[base2 +  0] = v6[2];
        *(u16x8*)&obt[base2 +  8] = v6[3];
        *(u16x8*)&obt[base2 + 16] = v6[4];
        *(u16x8*)&obt[base2 + 24] = v6[5];
    }
}

// ---------------------------------------------------------------------------
// 4) out GEMM + residual, BK=64, fused split-K combine in the staging:
//    al[n][c] = w0*obt0 + (1-w0)*obt1, w0 = l0/(l0+l1); head h = 2ks+(part>>2).
// ---------------------------------------------------------------------------
__global__ __launch_bounds__(256) void out_gemm_kernel(
    const u16* __restrict__ obt, const float* __restrict__ lP,
    const u16* __restrict__ wb, const float* __restrict__ x,
    float* __restrict__ out)
{
    const int nt = blockIdx.x, ot = blockIdx.y, bi = blockIdx.z;
    const int b = bi / 3, i = bi % 3;

    const u16* p0 = obt + ((size_t)bi * Nc) * 256;            // half 0
    const u16* p1 = obt + (((size_t)12 + bi) * Nc) * 256;     // half 1
    const u16* ws = wb + (size_t)(768 + ot * 128) * 256;

    __shared__ u16 al[128][72];
    __shared__ u16 wl[128][72];

    const int t = (int)threadIdx.x;
    const int wv = t >> 6, lane = t & 63;
    const int g = lane >> 4, c16 = lane & 15;
    const int wr = wv >> 1, wc = wv & 1;

    f32x4 acc[4][4];
#pragma unroll
    for (int mi = 0; mi < 4; ++mi)
#pragma unroll
        for (int ni = 0; ni < 4; ++ni)
#pragma unroll
            for (int r = 0; r < 4; ++r) acc[mi][ni][r] = 0.f;

    for (int ks = 0; ks < 4; ++ks) {
        __syncthreads();
#pragma unroll
        for (int it = 0; it < 4; ++it) {
            const int idx = t + it * 256;
            const int row = idx >> 3, part = idx & 7;
            const int n = nt * 128 + row;
            const int h = 2 * ks + (part >> 2);
            const float l0 = lP[((size_t)(b * 8 + h)) * Nc + n];
            const float l1 = lP[((size_t)(32 + b * 8 + h)) * Nc + n];
            const float w0 = l0 / (l0 + l1);
            const float w1 = 1.f - w0;
            const u16x8 a0 = *(const u16x8*)&p0[(size_t)n * 256 + ks * 64 + part * 8];
            const u16x8 a1 = *(const u16x8*)&p1[(size_t)n * 256 + ks * 64 + part * 8];
            u16x8 rr;
#pragma unroll
            for (int j = 0; j < 8; ++j)
                rr[j] = f2bf(bf2f(a0[j]) * w0 + bf2f(a1[j]) * w1);
            *(u16x8*)&al[row][part * 8] = rr;
            *(u16x8*)&wl[row][part * 8] =
                *(const u16x8*)&ws[(size_t)row * 256 + ks * 64 + part * 8];
        }
        __syncthreads();

#pragma unroll
        for (int kk = 0; kk < 2; ++kk) {
            s16x8 af[4], bf[4];
#pragma unroll
            for (int mi = 0; mi < 4; ++mi) af[mi] = *(const s16x8*)&wl[wr*64 + mi*16 + c16][kk*32 + g*8];
#pragma unroll
            for (int ni = 0; ni < 4; ++ni) bf[ni] = *(const s16x8*)&al[wc*64 + ni*16 + c16][kk*32 + g*8];
#pragma unroll
            for (int mi = 0; mi < 4; ++mi)
#pragma unroll
                for (int ni = 0; ni < 4; ++ni)
                    acc[mi][ni] = __builtin_amdgcn_mfma_f32_16x16x32_bf16(
                        af[mi], bf[ni], acc[mi][ni], 0, 0, 0);
        }
    }

#pragma unroll
    for (int mi = 0; mi < 4; ++mi)
#pragma unroll
        for (int ni = 0; ni < 4; ++ni) {
            const int n = nt * 128 + wc * 64 + ni * 16 + c16;
#pragma unroll
            for (int r = 0; r < 4; ++r) {
                const int o = ot * 128 + wr * 64 + mi * 16 + g * 4 + r;
                const size_t idx = ((size_t)(b * 256 + o) * 3 + i) * Nc + n;
                out[idx] = x[idx] + acc[mi][ni][r];
            }
        }
}

// ---------------------------------------------------------------------------
extern "C" void kernel_launch(void* const* d_in, const int* in_sizes, int n_in,
                              void* d_out, int out_size, void* d_ws, size_t ws_size,
                              hipStream_t stream) {
    const float* x  = (const float*)d_in[0];
    const float* Wq = (const float*)d_in[1];
    const float* Wk = (const float*)d_in[2];
    const float* Wv = (const float*)d_in[3];
    const float* Wo = (const float*)d_in[4];
    float* out = (float*)d_out;

    const size_t E = (size_t)32 * Fc * Nc;       // 6,291,456 u16
    u16* xt  = (u16*)d_ws;                        // E
    u16* wbw = xt + E;                            // 262144
    u16* qt  = wbw + 262144;                      // E
    u16* kt  = qt + E;                            // E
    u16* vf  = kt + E;                            // E
    u16* obt = vf + E;                            // 2*E (token-major partials)
    float* lP = (float*)(obt + 2 * E);            // 131072 floats

    dim3 blk(256);
    prep_kernel     <<<dim3(128 + 1536), blk, 0, stream>>>(x, Wq, Wk, Wv, Wo, wbw, xt);
    qkv_gemm_kernel <<<dim3(16, 6, 12),  blk, 0, stream>>>(xt, wbw, qt, kt, vf);
    attn_mfma_kernel<<<dim3(1024),       blk, 0, stream>>>(qt, kt, vf, obt, lP);
    out_gemm_kernel <<<dim3(16, 2, 12),  blk, 0, stream>>>(obt, lP, wbw, x, out);
}